// Round 1
// baseline (37078.601 us; speedup 1.0000x reference)
//
#include <hip/hip_runtime.h>
#include <hip/hip_bf16.h>
#include <stdint.h>

// SubLSTM: T=1024, B=64, H=512, GATE=3H, L=2.
// Batch-partitioned persistent recurrence:
//   8 groups x 8 batch rows; 32 CUs per group (16 h-cols each -> 48 gate rows).
//   256 WGs x 192 threads (3 waves = i/o/z gate chunks). Weights preloaded as
//   MFMA B-fragments in VGPRs. Per-step cross-CU exchange of h slices through
//   global memory with per-group monotonic counters (release/acquire, agent
//   scope -> cross-XCD correct). Layer 0 kernel writes bf16 h0 history to ws;
//   layer 1 kernel (second launch) consumes it and emits f32 output.

#define TSTEPS 1024
#define BATCH  64
#define HID    512
#define GATE   1536
#define NLAYERS 2
#define NGROUPS 8
#define GROWS   8     // batch rows per group
#define GCUS    32    // CUs (blocks) per group
#define NTHREADS 192  // 3 waves

typedef __attribute__((ext_vector_type(8))) short short8;
typedef __attribute__((ext_vector_type(4))) short short4v;
typedef __attribute__((ext_vector_type(4))) float floatx4;

__device__ __forceinline__ float sigmoidf_(float x) { return 1.0f / (1.0f + __expf(-x)); }

__device__ __forceinline__ unsigned short f2bf(float x) {
    union { float f; unsigned u; } v; v.f = x;
    unsigned r = v.u + 0x7FFFu + ((v.u >> 16) & 1u);   // RNE
    return (unsigned short)(r >> 16);
}

__global__ __launch_bounds__(NTHREADS, 1) void sublstm_layer(
    const int layer,
    const float* __restrict__ x,
    const float* __restrict__ W,
    const float* __restrict__ R,
    const float* __restrict__ bi,
    const float* __restrict__ bh,
    const float* __restrict__ fw,
    const float* __restrict__ h0,
    const float* __restrict__ c0,
    unsigned short* __restrict__ hist,   // bf16 h0 history in ws
    float* __restrict__ out,             // d_out: [T*B*H | h_f L*B*H | c_f L*B*H]
    unsigned* __restrict__ counters)
{
    const int tid  = threadIdx.x;
    const int lane = tid & 63;
    const int wid  = tid >> 6;            // 0=i_g, 1=o_g, 2=z
    const int bid  = blockIdx.x;
    const int g    = bid & 7;             // batch group (XCD-local heuristic)
    const int idx  = bid >> 3;            // 0..31: which 16 h-cols
    const int col0 = idx << 4;

    __shared__ unsigned short inp_tile[16][520];  // padded stride (1040B)
    __shared__ unsigned short h_tile[16][520];
    __shared__ float proj[3][16][17];

    for (int i = tid; i < 16*520; i += NTHREADS) {
        ((unsigned short*)inp_tile)[i] = 0;
        ((unsigned short*)h_tile)[i]   = 0;
    }
    __syncthreads();

    // MFMA 16x16x32 bf16 lane mapping:
    //   A: row = lane&15, k = (lane>>4)*8 + j   (j=0..7)
    //   B: col = lane&15, same k positions       (consistency is what matters)
    //   D: col = lane&15, row = (lane>>4)*4 + q  (m89-verified)
    const int lrow = lane & 15;
    const int lk   = (lane >> 4) << 3;
    const int wrow = wid*HID + col0 + lrow;       // gate row owned by this lane-col

    const float* Wl = W + (size_t)layer*GATE*HID;
    const float* Rl = R + (size_t)layer*GATE*HID;

    // Preload weight fragments into registers (128 VGPRs).
    short8 wf[16], rf[16];
#pragma unroll
    for (int kc = 0; kc < 16; ++kc) {
        const float* wp = Wl + (size_t)wrow*HID + kc*32 + lk;
        const float* rp = Rl + (size_t)wrow*HID + kc*32 + lk;
        floatx4 w0 = *(const floatx4*)(wp);
        floatx4 w1 = *(const floatx4*)(wp + 4);
        floatx4 r0 = *(const floatx4*)(rp);
        floatx4 r1 = *(const floatx4*)(rp + 4);
        short8 a, b;
#pragma unroll
        for (int j = 0; j < 4; ++j) {
            a[j]   = (short)f2bf(w0[j]);
            a[j+4] = (short)f2bf(w1[j]);
            b[j]   = (short)f2bf(r0[j]);
            b[j+4] = (short)f2bf(r1[j]);
        }
        wf[kc] = a; rf[kc] = b;
    }

    const float bias = bi[(size_t)layer*GATE + wrow] + bh[(size_t)layer*GATE + wrow];
    const int  ecol  = lrow;
    const int  erow0 = (lane >> 4) << 2;
    const float fgv  = sigmoidf_(fw[(size_t)layer*HID + col0 + ecol]);

    // c state lives in wave-0 registers (lane<->element fixed by D layout).
    float creg[4];
#pragma unroll
    for (int q = 0; q < 4; ++q) {
        int r = erow0 + q;
        creg[q] = (r < GROWS) ? c0[((size_t)layer*BATCH + g*GROWS + r)*HID + col0 + ecol] : 0.0f;
    }

    // h_tile <- h0 init (rows 8..15 stay zero forever)
    for (int i = tid; i < GROWS*HID; i += NTHREADS) {
        int r = i >> 9, k = i & 511;
        h_tile[r][k] = f2bf(h0[((size_t)layer*BATCH + g*GROWS + r)*HID + k]);
    }
    __syncthreads();

    unsigned* ctr = counters + ((layer << 3) + g) * 64;   // 256B-strided counters
    long budget = 20000000;                               // deadlock safety bail

    for (int t = 0; t < TSTEPS; ++t) {
        // ---- Phase A: stage input tile (no recurrence dependency) ----
        if (layer == 0) {
            const float* xp = x + ((size_t)t*BATCH + g*GROWS)*HID;
            for (int i = tid; i < GROWS*HID/4; i += NTHREADS) {
                int r = i >> 7, k4 = (i & 127) << 2;
                floatx4 v = *(const floatx4*)(xp + (size_t)r*HID + k4);
                short4v p;
                p[0]=(short)f2bf(v[0]); p[1]=(short)f2bf(v[1]);
                p[2]=(short)f2bf(v[2]); p[3]=(short)f2bf(v[3]);
                *(short4v*)(&inp_tile[r][k4]) = p;
            }
        } else {
            const unsigned short* hp = hist + ((size_t)t*BATCH + g*GROWS)*HID;
            for (int i = tid; i < GROWS*HID/8; i += NTHREADS) {
                int r = i >> 6, k8 = (i & 63) << 3;
                *(short8*)(&inp_tile[r][k8]) = *(const short8*)(hp + (size_t)r*HID + k8);
            }
        }
        __syncthreads();

        floatx4 acc = {0.f, 0.f, 0.f, 0.f};
#pragma unroll
        for (int kc = 0; kc < 16; ++kc) {
            short8 af = *(const short8*)(&inp_tile[lrow][kc*32 + lk]);
            acc = __builtin_amdgcn_mfma_f32_16x16x32_bf16(af, wf[kc], acc, 0, 0, 0);
        }

        // ---- Phase B: wait for h_{t-1} from the group's 32 CUs ----
        if (t > 0) {
            if (tid == 0) {
                const unsigned target = (unsigned)(GCUS * t);
                while (__hip_atomic_load(ctr, __ATOMIC_ACQUIRE, __HIP_MEMORY_SCOPE_AGENT) < target) {
                    if (--budget < 0) break;
                }
            }
            __syncthreads();
            if (layer == 0) {
                const unsigned short* hp = hist + ((size_t)(t-1)*BATCH + g*GROWS)*HID;
                for (int i = tid; i < GROWS*HID/8; i += NTHREADS) {
                    int r = i >> 6, k8 = (i & 63) << 3;
                    *(short8*)(&h_tile[r][k8]) = *(const short8*)(hp + (size_t)r*HID + k8);
                }
            } else {
                const float* hp = out + ((size_t)(t-1)*BATCH + g*GROWS)*HID;
                for (int i = tid; i < GROWS*HID/4; i += NTHREADS) {
                    int r = i >> 7, k4 = (i & 127) << 2;
                    floatx4 v = *(const floatx4*)(hp + (size_t)r*HID + k4);
                    short4v p;
                    p[0]=(short)f2bf(v[0]); p[1]=(short)f2bf(v[1]);
                    p[2]=(short)f2bf(v[2]); p[3]=(short)f2bf(v[3]);
                    *(short4v*)(&h_tile[r][k4]) = p;
                }
            }
            __syncthreads();
        }

#pragma unroll
        for (int kc = 0; kc < 16; ++kc) {
            short8 af = *(const short8*)(&h_tile[lrow][kc*32 + lk]);
            acc = __builtin_amdgcn_mfma_f32_16x16x32_bf16(af, rf[kc], acc, 0, 0, 0);
        }

        // ---- Phase C: sigmoid + i/o/z cross-wave exchange + state update ----
#pragma unroll
        for (int q = 0; q < 4; ++q)
            proj[wid][erow0 + q][ecol] = sigmoidf_(acc[q] + bias);
        __syncthreads();

        if (wid == 0) {
#pragma unroll
            for (int q = 0; q < 4; ++q) {
                const int r = erow0 + q;
                const float ig = proj[0][r][ecol];
                const float og = proj[1][r][ecol];
                const float zz = proj[2][r][ecol];
                const float c  = creg[q]*fgv + zz - ig;
                creg[q] = c;
                const float h  = sigmoidf_(c) - og;
                if (r < GROWS) {
                    const size_t off = ((size_t)t*BATCH + g*GROWS + r)*HID + col0 + ecol;
                    if (layer == 0) hist[off] = f2bf(h);
                    else            out[off] = h;
                    if (t == TSTEPS-1) {
                        const size_t fo = (size_t)TSTEPS*BATCH*HID
                                        + ((size_t)layer*BATCH + g*GROWS + r)*HID + col0 + ecol;
                        out[fo] = h;                               // h_f
                        out[fo + (size_t)NLAYERS*BATCH*HID] = c;   // c_f
                    }
                }
            }
        }
        __threadfence();          // publish h slice (agent scope, cross-XCD)
        __syncthreads();
        if (tid == 0) atomicAdd(ctr, 1u);   // counter release (fenced above)
    }
}

extern "C" void kernel_launch(void* const* d_in, const int* in_sizes, int n_in,
                              void* d_out, int out_size, void* d_ws, size_t ws_size,
                              hipStream_t stream)
{
    (void)in_sizes; (void)n_in; (void)out_size; (void)ws_size;
    const float* x  = (const float*)d_in[0];
    const float* h0 = (const float*)d_in[1];
    const float* c0 = (const float*)d_in[2];
    const float* W  = (const float*)d_in[3];
    const float* R  = (const float*)d_in[4];
    const float* bi = (const float*)d_in[5];
    const float* bh = (const float*)d_in[6];
    const float* fw = (const float*)d_in[7];
    float* out = (float*)d_out;

    unsigned* counters   = (unsigned*)d_ws;
    unsigned short* hist = (unsigned short*)((char*)d_ws + 8192);  // 64 MiB bf16 h0 history

    hipMemsetAsync(d_ws, 0, 8192, stream);  // reset counters every call (replay-safe)

    sublstm_layer<<<dim3(NGROUPS*GCUS), dim3(NTHREADS), 0, stream>>>(
        0, x, W, R, bi, bh, fw, h0, c0, hist, out, counters);
    sublstm_layer<<<dim3(NGROUPS*GCUS), dim3(NTHREADS), 0, stream>>>(
        1, x, W, R, bi, bh, fw, h0, c0, hist, out, counters);
}

// Round 2
// 18164.365 us; speedup vs baseline: 2.0413x; 2.0413x over previous
//
#include <hip/hip_runtime.h>
#include <hip/hip_bf16.h>
#include <stdint.h>

// SubLSTM T=1024, B=64, H=512, GATE=3H, L=2 — fused 2-layer pipelined version.
//
// 8 batch-groups x 8 rows; 32 blocks per group, each owning 16 h-cols of BOTH
// layers (weights for both layers preloaded in VGPRs: 256 VGPR/thread).
// Per iteration i: L0 computes t=i, L1 computes t=i-1 (layer pipelining, lag 1).
// Cross-block h exchange via tag-in-band u32 words ((bf16<<16)|(t+1)) in two
// 2-deep rings, relaxed agent-scope stores/loads — NO fences, NO atomic RMW.
// Replay-safe: every (slot,addr) is rewritten with a deterministic value; a
// stale tag match implies an identical stale value.

#define TSTEPS 1024
#define BATCH  64
#define HID    512
#define GATE   1536
#define NGROUPS 8
#define GROWS   8
#define GCUS    32
#define NTHREADS 192
#define RINGW   (2*BATCH*HID)            // u32 words per ring (2 slots)
#define POLLW   ((2*GROWS*HID + NTHREADS - 1)/NTHREADS)   // 43

typedef __attribute__((ext_vector_type(8))) short short8;
typedef __attribute__((ext_vector_type(4))) short short4v;
typedef __attribute__((ext_vector_type(4))) float floatx4;

__device__ __forceinline__ float sigmoidf_(float x) { return 1.0f / (1.0f + __expf(-x)); }

__device__ __forceinline__ unsigned short f2bf(float x) {
    union { float f; unsigned u; } v; v.f = x;
    unsigned r = v.u + 0x7FFFu + ((v.u >> 16) & 1u);   // RNE
    return (unsigned short)(r >> 16);
}

__device__ __forceinline__ short8 load_frag(const float* p) {
    floatx4 a = *(const floatx4*)p;
    floatx4 b = *(const floatx4*)(p + 4);
    short8 r;
#pragma unroll
    for (int j = 0; j < 4; ++j) { r[j] = (short)f2bf(a[j]); r[j+4] = (short)f2bf(b[j]); }
    return r;
}

__global__ __launch_bounds__(NTHREADS, 1) void sublstm_fused(
    const float* __restrict__ x,
    const float* __restrict__ W,
    const float* __restrict__ R,
    const float* __restrict__ bi,
    const float* __restrict__ bh,
    const float* __restrict__ fw,
    const float* __restrict__ h0,
    const float* __restrict__ c0,
    unsigned* __restrict__ ring0,
    unsigned* __restrict__ ring1,
    float* __restrict__ out)
{
    const int tid  = threadIdx.x;
    const int lane = tid & 63;
    const int wid  = tid >> 6;           // 0=i_g, 1=o_g, 2=z (gate owner)
    const int bid  = blockIdx.x;
    const int g    = bid & 7;            // batch group (XCD-affine heuristic)
    const int idx  = bid >> 3;           // 0..31: 16-col slice
    const int col0 = idx << 4;

    __shared__ unsigned short x_tile[16][520];
    __shared__ unsigned short hA[16][520];    // h0-layer tile (h0_{i-1})
    __shared__ unsigned short hB[16][520];    // h1-layer tile (h1_{i-2})
    __shared__ float proj[2][3][16][17];      // [layer][gate][row][col]

    for (int i = tid; i < 16*520; i += NTHREADS) {
        ((unsigned short*)x_tile)[i] = 0;
        ((unsigned short*)hA)[i] = 0;
        ((unsigned short*)hB)[i] = 0;
    }

    const int lrow = lane & 15;
    const int lk   = (lane >> 4) << 3;
    const int wrow = wid*HID + col0 + lrow;   // gate row within a layer

    // ---- Preload weight fragments for BOTH layers (256 VGPRs) ----
    short8 wf0[16], rf0[16], wf1[16], rf1[16];
#pragma unroll
    for (int kc = 0; kc < 16; ++kc) {
        wf0[kc] = load_frag(W + (size_t)wrow*HID + kc*32 + lk);
        rf0[kc] = load_frag(R + (size_t)wrow*HID + kc*32 + lk);
        wf1[kc] = load_frag(W + ((size_t)GATE + wrow)*HID + kc*32 + lk);
        rf1[kc] = load_frag(R + ((size_t)GATE + wrow)*HID + kc*32 + lk);
    }
    const float bias0 = bi[wrow] + bh[wrow];
    const float bias1 = bi[GATE + wrow] + bh[GATE + wrow];

    const int ecol  = lrow;
    const int erow0 = (lane >> 4) << 2;
    // wave 0 updates layer 0 state; wave 1 updates layer 1 state
    const int myl = (wid == 1) ? 1 : 0;
    const float fgv = sigmoidf_(fw[(size_t)myl*HID + col0 + ecol]);
    float creg[4];
#pragma unroll
    for (int q = 0; q < 4; ++q) {
        int r = erow0 + q;
        creg[q] = (r < GROWS) ? c0[((size_t)myl*BATCH + g*GROWS + r)*HID + col0 + ecol] : 0.0f;
    }

    // ---- Stage x_0 and h-state inits ----
    {
        const float* xp = x + (size_t)g*GROWS*HID;                // t=0
        const float* hp0 = h0 + (size_t)g*GROWS*HID;              // layer 0
        const float* hp1 = h0 + ((size_t)BATCH + g*GROWS)*HID;    // layer 1
#pragma unroll
        for (int k = 0; k < 6; ++k) {
            int w = tid + k*NTHREADS;
            if (w < GROWS*HID/4) {
                int r = w >> 7, c4 = (w & 127) << 2;
                floatx4 vx = *(const floatx4*)(xp  + (size_t)r*HID + c4);
                floatx4 va = *(const floatx4*)(hp0 + (size_t)r*HID + c4);
                floatx4 vb = *(const floatx4*)(hp1 + (size_t)r*HID + c4);
                short4v px, pa, pb;
#pragma unroll
                for (int j = 0; j < 4; ++j) {
                    px[j] = (short)f2bf(vx[j]); pa[j] = (short)f2bf(va[j]); pb[j] = (short)f2bf(vb[j]);
                }
                *(short4v*)(&x_tile[r][c4]) = px;
                *(short4v*)(&hA[r][c4])     = pa;
                *(short4v*)(&hB[r][c4])     = pb;
            }
        }
    }
    __syncthreads();

    int budget = 1 << 23;   // global spin budget (bail -> wrong answer, no hang)

    for (int i = 0; i <= TSTEPS; ++i) {
        floatx4 acc0 = {0.f,0.f,0.f,0.f};
        floatx4 acc1 = {0.f,0.f,0.f,0.f};

        if (i < TSTEPS) {            // L0 gates for t=i: x_i W0 + h0_{i-1} R0
#pragma unroll
            for (int kc = 0; kc < 16; ++kc) {
                short8 af = *(const short8*)(&x_tile[lrow][kc*32 + lk]);
                acc0 = __builtin_amdgcn_mfma_f32_16x16x32_bf16(af, wf0[kc], acc0, 0, 0, 0);
            }
#pragma unroll
            for (int kc = 0; kc < 16; ++kc) {
                short8 af = *(const short8*)(&hA[lrow][kc*32 + lk]);
                acc0 = __builtin_amdgcn_mfma_f32_16x16x32_bf16(af, rf0[kc], acc0, 0, 0, 0);
            }
        }
        if (i >= 1) {                // L1 gates for t=i-1: h0_{i-1} W1 + h1_{i-2} R1
#pragma unroll
            for (int kc = 0; kc < 16; ++kc) {
                short8 af = *(const short8*)(&hA[lrow][kc*32 + lk]);
                acc1 = __builtin_amdgcn_mfma_f32_16x16x32_bf16(af, wf1[kc], acc1, 0, 0, 0);
            }
#pragma unroll
            for (int kc = 0; kc < 16; ++kc) {
                short8 af = *(const short8*)(&hB[lrow][kc*32 + lk]);
                acc1 = __builtin_amdgcn_mfma_f32_16x16x32_bf16(af, rf1[kc], acc1, 0, 0, 0);
            }
        }

#pragma unroll
        for (int q = 0; q < 4; ++q) {
            proj[0][wid][erow0 + q][ecol] = sigmoidf_(acc0[q] + bias0);
            proj[1][wid][erow0 + q][ecol] = sigmoidf_(acc1[q] + bias1);
        }
        __syncthreads();

        // ---- state update + publish (wave0: L0 t=i, wave1: L1 t=i-1) ----
        if (wid < 2) {
            const int t = i - wid;
            if (t >= 0 && t < TSTEPS) {
                unsigned* ring = (wid == 0) ? ring0 : ring1;
                const int slot = t & 1;
                unsigned* rbase = ring + (((size_t)slot*BATCH + g*GROWS) << 9);
#pragma unroll
                for (int q = 0; q < 4; ++q) {
                    const int r = erow0 + q;
                    if (r < GROWS) {
                        const float ig = proj[wid][0][r][ecol];
                        const float og = proj[wid][1][r][ecol];
                        const float zz = proj[wid][2][r][ecol];
                        const float c  = creg[q]*fgv + zz - ig;
                        creg[q] = c;
                        const float h  = sigmoidf_(c) - og;
                        const unsigned word = ((unsigned)f2bf(h) << 16) | (unsigned)(t + 1);
                        __hip_atomic_store(rbase + ((size_t)r << 9) + col0 + ecol, word,
                                           __ATOMIC_RELAXED, __HIP_MEMORY_SCOPE_AGENT);
                        if (wid == 1)
                            out[((size_t)t*BATCH + g*GROWS + r)*HID + col0 + ecol] = h;
                        if (t == TSTEPS - 1) {
                            const size_t fo = (size_t)TSTEPS*BATCH*HID
                                            + ((size_t)wid*BATCH + g*GROWS + r)*HID + col0 + ecol;
                            out[fo] = h;                                  // h_f
                            out[fo + (size_t)2*BATCH*HID] = c;            // c_f
                        }
                    }
                }
            }
        }

        if (i < TSTEPS) {
            // ---- prefetch x_{i+1} into regs (hides HBM under the poll) ----
            floatx4 xr[6];
            const bool havex = (i + 1 < TSTEPS);
            if (havex) {
                const float* xp = x + ((size_t)(i+1)*BATCH + g*GROWS)*HID;
#pragma unroll
                for (int k = 0; k < 6; ++k) {
                    int w = tid + k*NTHREADS;
                    if (w < GROWS*HID/4)
                        xr[k] = *(const floatx4*)(xp + ((size_t)(w >> 7))*HID + ((w & 127) << 2));
                }
            }

            // ---- poll h0_i (tag i+1) and, for i>=1, h1_{i-1} (tag i) ----
            const unsigned wantA = (unsigned)(i + 1);
            const unsigned wantB = (unsigned)i;
            const int nw = (i >= 1) ? 2*GROWS*HID : GROWS*HID;
            const unsigned* pA = ring0 + ((((size_t)(i & 1))*BATCH + g*GROWS) << 9);
            const unsigned* pB = ring1 + ((((size_t)((i - 1) & 1))*BATCH + g*GROWS) << 9);
            unsigned va[POLLW];
            bool ok;
            int first = 1;
            do {
                ok = true;
#pragma unroll
                for (int k = 0; k < POLLW; ++k) {
                    const int w = tid + k*NTHREADS;
                    if (w < nw) {
                        const bool isA = (w < GROWS*HID);
                        const unsigned want = isA ? wantA : wantB;
                        if (first || ((va[k] & 0xFFFFu) != want)) {
                            const unsigned* p = isA ? (pA + w) : (pB + (w - GROWS*HID));
                            va[k] = __hip_atomic_load(p, __ATOMIC_RELAXED, __HIP_MEMORY_SCOPE_AGENT);
                        }
                        if ((va[k] & 0xFFFFu) != want) ok = false;
                    }
                }
                first = 0;
            } while (!__all((int)ok) && --budget > 0);

            // ---- stash polled h into LDS tiles, x regs into x_tile ----
#pragma unroll
            for (int k = 0; k < POLLW; ++k) {
                const int w = tid + k*NTHREADS;
                if (w < nw) {
                    const unsigned short hv = (unsigned short)(va[k] >> 16);
                    if (w < GROWS*HID) { hA[w >> 9][w & 511] = hv; }
                    else { const int ww = w - GROWS*HID; hB[ww >> 9][ww & 511] = hv; }
                }
            }
            if (havex) {
#pragma unroll
                for (int k = 0; k < 6; ++k) {
                    int w = tid + k*NTHREADS;
                    if (w < GROWS*HID/4) {
                        int r = w >> 7, c4 = (w & 127) << 2;
                        short4v p4;
#pragma unroll
                        for (int j = 0; j < 4; ++j) p4[j] = (short)f2bf(xr[k][j]);
                        *(short4v*)(&x_tile[r][c4]) = p4;
                    }
                }
            }
        }
        __syncthreads();
    }
}

extern "C" void kernel_launch(void* const* d_in, const int* in_sizes, int n_in,
                              void* d_out, int out_size, void* d_ws, size_t ws_size,
                              hipStream_t stream)
{
    (void)in_sizes; (void)n_in; (void)out_size; (void)ws_size;
    const float* x  = (const float*)d_in[0];
    const float* h0 = (const float*)d_in[1];
    const float* c0 = (const float*)d_in[2];
    const float* W  = (const float*)d_in[3];
    const float* R  = (const float*)d_in[4];
    const float* bi = (const float*)d_in[5];
    const float* bh = (const float*)d_in[6];
    const float* fw = (const float*)d_in[7];
    float* out = (float*)d_out;

    unsigned* ring0 = (unsigned*)d_ws;            // 256 KB
    unsigned* ring1 = ring0 + RINGW;              // 256 KB

    sublstm_fused<<<dim3(NGROUPS*GCUS), dim3(NTHREADS), 0, stream>>>(
        x, W, R, bi, bh, fw, h0, c0, ring0, ring1, out);
}

// Round 3
// 8726.747 us; speedup vs baseline: 4.2488x; 2.0815x over previous
//
#include <hip/hip_runtime.h>
#include <hip/hip_bf16.h>
#include <stdint.h>

// SubLSTM T=1024, B=64, H=512, GATE=3H, L=2 — fused 2-layer pipelined version.
//
// 8 batch-groups x 8 rows; 32 blocks per group, each owning 16 h-cols of BOTH
// layers (weights for both layers preloaded in VGPR/AGPR: 256 regs/thread).
// Per iteration i: L0 computes t=i, L1 computes t=i-1 (layer pipelining, lag 1).
// Cross-block h exchange via tag-in-band u32 words ((bf16<<16)|(t+1)) in two
// 2-deep rings, relaxed agent-scope stores/loads — NO fences, NO atomic RMW.
// Poll is a two-phase batched sweep: issue ALL loads unconditionally (one
// vmcnt drain ~ one LLC roundtrip), THEN check tags. (Round-2 lesson: a
// conditional reload guard serializes 43 x ~600cy LLC loads per sweep.)
// Replay-safe: tags are monotone within a replay; stale previous-replay tags
// never alias a wanted tag before being overwritten (slots cycle every 2 steps).

#define TSTEPS 1024
#define BATCH  64
#define HID    512
#define GATE   1536
#define NGROUPS 8
#define GROWS   8
#define GCUS    32
#define NTHREADS 192
#define RINGW   (2*BATCH*HID)            // u32 words per ring (2 slots)
#define POLLW   ((2*GROWS*HID + NTHREADS - 1)/NTHREADS)   // 43

typedef __attribute__((ext_vector_type(8))) short short8;
typedef __attribute__((ext_vector_type(4))) short short4v;
typedef __attribute__((ext_vector_type(4))) float floatx4;

__device__ __forceinline__ float sigmoidf_(float x) { return 1.0f / (1.0f + __expf(-x)); }

__device__ __forceinline__ unsigned short f2bf(float x) {
    union { float f; unsigned u; } v; v.f = x;
    unsigned r = v.u + 0x7FFFu + ((v.u >> 16) & 1u);   // RNE
    return (unsigned short)(r >> 16);
}

__device__ __forceinline__ short8 load_frag(const float* p) {
    floatx4 a = *(const floatx4*)p;
    floatx4 b = *(const floatx4*)(p + 4);
    short8 r;
#pragma unroll
    for (int j = 0; j < 4; ++j) { r[j] = (short)f2bf(a[j]); r[j+4] = (short)f2bf(b[j]); }
    return r;
}

__global__ __launch_bounds__(NTHREADS, 1) void sublstm_fused(
    const float* __restrict__ x,
    const float* __restrict__ W,
    const float* __restrict__ R,
    const float* __restrict__ bi,
    const float* __restrict__ bh,
    const float* __restrict__ fw,
    const float* __restrict__ h0,
    const float* __restrict__ c0,
    unsigned* __restrict__ ring0,
    unsigned* __restrict__ ring1,
    float* __restrict__ out)
{
    const int tid  = threadIdx.x;
    const int lane = tid & 63;
    const int wid  = tid >> 6;           // 0=i_g, 1=o_g, 2=z (gate owner)
    const int bid  = blockIdx.x;
    const int g    = bid & 7;            // batch group (XCD-affine heuristic)
    const int idx  = bid >> 3;           // 0..31: 16-col slice
    const int col0 = idx << 4;

    __shared__ unsigned short x_tile[16][520];
    __shared__ unsigned short hA[16][520];    // h0-layer tile (h0_{i-1})
    __shared__ unsigned short hB[16][520];    // h1-layer tile (h1_{i-2})
    __shared__ float proj[2][3][16][17];      // [layer][gate][row][col]

    for (int i = tid; i < 16*520; i += NTHREADS) {
        ((unsigned short*)x_tile)[i] = 0;
        ((unsigned short*)hA)[i] = 0;
        ((unsigned short*)hB)[i] = 0;
    }

    const int lrow = lane & 15;
    const int lk   = (lane >> 4) << 3;
    const int wrow = wid*HID + col0 + lrow;   // gate row within a layer

    // ---- Preload weight fragments for BOTH layers ----
    short8 wf0[16], rf0[16], wf1[16], rf1[16];
#pragma unroll
    for (int kc = 0; kc < 16; ++kc) {
        wf0[kc] = load_frag(W + (size_t)wrow*HID + kc*32 + lk);
        rf0[kc] = load_frag(R + (size_t)wrow*HID + kc*32 + lk);
        wf1[kc] = load_frag(W + ((size_t)GATE + wrow)*HID + kc*32 + lk);
        rf1[kc] = load_frag(R + ((size_t)GATE + wrow)*HID + kc*32 + lk);
    }
    const float bias0 = bi[wrow] + bh[wrow];
    const float bias1 = bi[GATE + wrow] + bh[GATE + wrow];

    const int ecol  = lrow;
    const int erow0 = (lane >> 4) << 2;
    const int myl = (wid == 1) ? 1 : 0;       // wave0 -> L0 state, wave1 -> L1 state
    const float fgv = sigmoidf_(fw[(size_t)myl*HID + col0 + ecol]);
    float creg[4];
#pragma unroll
    for (int q = 0; q < 4; ++q) {
        int r = erow0 + q;
        creg[q] = (r < GROWS) ? c0[((size_t)myl*BATCH + g*GROWS + r)*HID + col0 + ecol] : 0.0f;
    }

    // ---- Stage x_0 and h-state inits ----
    {
        const float* xp  = x + (size_t)g*GROWS*HID;               // t=0
        const float* hp0 = h0 + (size_t)g*GROWS*HID;              // layer 0
        const float* hp1 = h0 + ((size_t)BATCH + g*GROWS)*HID;    // layer 1
#pragma unroll
        for (int k = 0; k < 6; ++k) {
            int w = tid + k*NTHREADS;
            if (w < GROWS*HID/4) {
                int r = w >> 7, c4 = (w & 127) << 2;
                floatx4 vx = *(const floatx4*)(xp  + (size_t)r*HID + c4);
                floatx4 va = *(const floatx4*)(hp0 + (size_t)r*HID + c4);
                floatx4 vb = *(const floatx4*)(hp1 + (size_t)r*HID + c4);
                short4v px, pa, pb;
#pragma unroll
                for (int j = 0; j < 4; ++j) {
                    px[j] = (short)f2bf(vx[j]); pa[j] = (short)f2bf(va[j]); pb[j] = (short)f2bf(vb[j]);
                }
                *(short4v*)(&x_tile[r][c4]) = px;
                *(short4v*)(&hA[r][c4])     = pa;
                *(short4v*)(&hB[r][c4])     = pb;
            }
        }
    }
    __syncthreads();

    int budget = 1 << 23;   // spin-sweep budget (bail -> wrong answer, no hang)

    for (int i = 0; i <= TSTEPS; ++i) {
        floatx4 acc0 = {0.f,0.f,0.f,0.f};
        floatx4 acc1 = {0.f,0.f,0.f,0.f};

        if (i < TSTEPS) {            // L0 gates for t=i: x_i W0 + h0_{i-1} R0
#pragma unroll
            for (int kc = 0; kc < 16; ++kc) {
                short8 af = *(const short8*)(&x_tile[lrow][kc*32 + lk]);
                acc0 = __builtin_amdgcn_mfma_f32_16x16x32_bf16(af, wf0[kc], acc0, 0, 0, 0);
            }
#pragma unroll
            for (int kc = 0; kc < 16; ++kc) {
                short8 af = *(const short8*)(&hA[lrow][kc*32 + lk]);
                acc0 = __builtin_amdgcn_mfma_f32_16x16x32_bf16(af, rf0[kc], acc0, 0, 0, 0);
            }
        }
        if (i >= 1) {                // L1 gates for t=i-1: h0_{i-1} W1 + h1_{i-2} R1
#pragma unroll
            for (int kc = 0; kc < 16; ++kc) {
                short8 af = *(const short8*)(&hA[lrow][kc*32 + lk]);
                acc1 = __builtin_amdgcn_mfma_f32_16x16x32_bf16(af, wf1[kc], acc1, 0, 0, 0);
            }
#pragma unroll
            for (int kc = 0; kc < 16; ++kc) {
                short8 af = *(const short8*)(&hB[lrow][kc*32 + lk]);
                acc1 = __builtin_amdgcn_mfma_f32_16x16x32_bf16(af, rf1[kc], acc1, 0, 0, 0);
            }
        }

#pragma unroll
        for (int q = 0; q < 4; ++q) {
            proj[0][wid][erow0 + q][ecol] = sigmoidf_(acc0[q] + bias0);
            proj[1][wid][erow0 + q][ecol] = sigmoidf_(acc1[q] + bias1);
        }
        __syncthreads();

        // ---- state update + publish (wave0: L0 t=i, wave1: L1 t=i-1) ----
        if (wid < 2) {
            const int t = i - wid;
            if (t >= 0 && t < TSTEPS) {
                unsigned* ring = (wid == 0) ? ring0 : ring1;
                const int slot = t & 1;
                unsigned* rbase = ring + (((size_t)slot*BATCH + g*GROWS) << 9);
#pragma unroll
                for (int q = 0; q < 4; ++q) {
                    const int r = erow0 + q;
                    if (r < GROWS) {
                        const float ig = proj[wid][0][r][ecol];
                        const float og = proj[wid][1][r][ecol];
                        const float zz = proj[wid][2][r][ecol];
                        const float c  = creg[q]*fgv + zz - ig;
                        creg[q] = c;
                        const float h  = sigmoidf_(c) - og;
                        const unsigned word = ((unsigned)f2bf(h) << 16) | (unsigned)(t + 1);
                        __hip_atomic_store(rbase + ((size_t)r << 9) + col0 + ecol, word,
                                           __ATOMIC_RELAXED, __HIP_MEMORY_SCOPE_AGENT);
                        if (wid == 1)
                            out[((size_t)t*BATCH + g*GROWS + r)*HID + col0 + ecol] = h;
                        if (t == TSTEPS - 1) {
                            const size_t fo = (size_t)TSTEPS*BATCH*HID
                                            + ((size_t)wid*BATCH + g*GROWS + r)*HID + col0 + ecol;
                            out[fo] = h;                                  // h_f
                            out[fo + (size_t)2*BATCH*HID] = c;            // c_f
                        }
                    }
                }
            }
        }

        if (i < TSTEPS) {
            // ---- stage x_{i+1} into LDS now (off the post-poll path; x_tile
            //      reads finished before the mid-iteration barrier) ----
            if (i + 1 < TSTEPS) {
                const float* xp = x + ((size_t)(i+1)*BATCH + g*GROWS)*HID;
#pragma unroll
                for (int k = 0; k < 6; ++k) {
                    int w = tid + k*NTHREADS;
                    if (w < GROWS*HID/4) {
                        int r = w >> 7, c4 = (w & 127) << 2;
                        floatx4 v = *(const floatx4*)(xp + (size_t)r*HID + c4);
                        short4v p4;
#pragma unroll
                        for (int j = 0; j < 4; ++j) p4[j] = (short)f2bf(v[j]);
                        *(short4v*)(&x_tile[r][c4]) = p4;
                    }
                }
            }

            // ---- poll h0_i (tag i+1) and, for i>=1, h1_{i-1} (tag i) ----
            // Two-phase batched sweep: ALL loads unconditionally, then check.
            const unsigned wantA = (unsigned)(i + 1);
            const unsigned wantB = (unsigned)i;
            const int nw = (i >= 1) ? 2*GROWS*HID : GROWS*HID;
            const unsigned* pA = ring0 + ((((size_t)(i & 1))*BATCH + g*GROWS) << 9);
            const unsigned* pB = ring1 + ((((size_t)((i - 1) & 1))*BATCH + g*GROWS) << 9);
            unsigned va[POLLW];
            while (true) {
#pragma unroll
                for (int k = 0; k < POLLW; ++k) {
                    const int w = tid + k*NTHREADS;
                    if (w < nw) {
                        const unsigned* p = (w < GROWS*HID) ? (pA + w)
                                                            : (pB + (w - GROWS*HID));
                        va[k] = __hip_atomic_load(p, __ATOMIC_RELAXED,
                                                  __HIP_MEMORY_SCOPE_AGENT);
                    }
                }
                bool ok = true;
#pragma unroll
                for (int k = 0; k < POLLW; ++k) {
                    const int w = tid + k*NTHREADS;
                    if (w < nw) {
                        const unsigned want = (w < GROWS*HID) ? wantA : wantB;
                        if ((va[k] & 0xFFFFu) != want) ok = false;
                    }
                }
                if (__all((int)ok) || --budget <= 0) break;
                __builtin_amdgcn_s_sleep(1);
            }

            // ---- stash polled h into LDS tiles ----
#pragma unroll
            for (int k = 0; k < POLLW; ++k) {
                const int w = tid + k*NTHREADS;
                if (w < nw) {
                    const unsigned short hv = (unsigned short)(va[k] >> 16);
                    if (w < GROWS*HID) { hA[w >> 9][w & 511] = hv; }
                    else { const int ww = w - GROWS*HID; hB[ww >> 9][ww & 511] = hv; }
                }
            }
        }
        __syncthreads();
    }
}

extern "C" void kernel_launch(void* const* d_in, const int* in_sizes, int n_in,
                              void* d_out, int out_size, void* d_ws, size_t ws_size,
                              hipStream_t stream)
{
    (void)in_sizes; (void)n_in; (void)out_size; (void)ws_size;
    const float* x  = (const float*)d_in[0];
    const float* h0 = (const float*)d_in[1];
    const float* c0 = (const float*)d_in[2];
    const float* W  = (const float*)d_in[3];
    const float* R  = (const float*)d_in[4];
    const float* bi = (const float*)d_in[5];
    const float* bh = (const float*)d_in[6];
    const float* fw = (const float*)d_in[7];
    float* out = (float*)d_out;

    unsigned* ring0 = (unsigned*)d_ws;            // 256 KB
    unsigned* ring1 = ring0 + RINGW;              // 256 KB

    sublstm_fused<<<dim3(NGROUPS*GCUS), dim3(NTHREADS), 0, stream>>>(
        x, W, R, bi, bh, fw, h0, c0, ring0, ring1, out);
}

// Round 4
// 7008.532 us; speedup vs baseline: 5.2905x; 1.2452x over previous
//
#include <hip/hip_runtime.h>
#include <hip/hip_bf16.h>
#include <stdint.h>

// SubLSTM T=1024, B=64, H=512, GATE=3H, L=2 — fused 2-layer pipelined version,
// round 4: sentinel-based sync (detection decoupled from data).
//
// Topology: 8 batch-groups x 8 rows; 32 blocks/group (16 h-cols each, both
// layers; weights in regs). Iteration i: L0 computes t=i, L1 computes t=i-1.
//
// Protocol per iteration (per block):
//   publish: packed u32 (2xbf16) relaxed agent-scope stores into depth-2 rings
//            -> __syncthreads (drains vmcnt(0) before s_barrier; vmem ops
//               complete IN ORDER per wave => all data at LLC)
//            -> tid0 stores sentinel = i+1 (relaxed agent, sc1)
//   detect:  wave2 spins on the group's 32 sentinels (one 64-lane gather,
//            16B stride, >= compare tolerates 1-step run-ahead)
//   fetch:   after barrier, ALL threads do ONE batched sweep of the 16KB
//            group tile (22 loads/thread) -> stash to LDS.
// Ring depth-2 overwrite safety: producer can publish slot s for step t+2 only
// after observing sentinel t+1 from every block, whose store (in-order vmcnt)
// completes after that block's slot-s loads of step t retired.
// Replay-safe: sentinels memset to 0 each call; values 1..1024 monotone.
//
// x is pre-converted f32->bf16 by a preamble kernel (removes per-round f2bf
// VALU from the serial path; halves x HBM traffic).

#define TSTEPS 1024
#define BATCH  64
#define HID    512
#define GATE   1536
#define NGROUPS 8
#define GROWS   8
#define GCUS    32
#define NTHREADS 192
#define SENT_STRIDE 4                         // u32 stride between sentinels (16 B)
#define RING_WORDS (2*BATCH*(HID/2))          // 32K u32 per ring (2 slots)
#define DATAW ((2*GROWS*(HID/2) + NTHREADS - 1)/NTHREADS)   // 22

typedef __attribute__((ext_vector_type(8))) short short8;
typedef __attribute__((ext_vector_type(4))) short short4v;
typedef __attribute__((ext_vector_type(4))) float floatx4;

__device__ __forceinline__ float sigmoidf_(float x) { return 1.0f / (1.0f + __expf(-x)); }

__device__ __forceinline__ unsigned short f2bf(float x) {
    union { float f; unsigned u; } v; v.f = x;
    unsigned r = v.u + 0x7FFFu + ((v.u >> 16) & 1u);   // RNE
    return (unsigned short)(r >> 16);
}

__device__ __forceinline__ short8 load_frag(const float* p) {
    floatx4 a = *(const floatx4*)p;
    floatx4 b = *(const floatx4*)(p + 4);
    short8 r;
#pragma unroll
    for (int j = 0; j < 4; ++j) { r[j] = (short)f2bf(a[j]); r[j+4] = (short)f2bf(b[j]); }
    return r;
}

// ---- preamble: x f32 -> bf16 (memory-bound, ~35 us) ----
__global__ __launch_bounds__(256) void xconvert(const float* __restrict__ x,
                                                unsigned short* __restrict__ xb) {
    const size_t i = ((size_t)blockIdx.x*256 + threadIdx.x) * 8;
    floatx4 a = *(const floatx4*)(x + i);
    floatx4 b = *(const floatx4*)(x + i + 4);
    short8 p;
#pragma unroll
    for (int j = 0; j < 4; ++j) { p[j] = (short)f2bf(a[j]); p[j+4] = (short)f2bf(b[j]); }
    *(short8*)(xb + i) = p;
}

__global__ __launch_bounds__(NTHREADS, 1) void sublstm_fused(
    const unsigned short* __restrict__ xb,
    const float* __restrict__ W,
    const float* __restrict__ R,
    const float* __restrict__ bi,
    const float* __restrict__ bh,
    const float* __restrict__ fw,
    const float* __restrict__ h0,
    const float* __restrict__ c0,
    unsigned* __restrict__ sent,
    unsigned* __restrict__ ring0,
    unsigned* __restrict__ ring1,
    float* __restrict__ out)
{
    const int tid  = threadIdx.x;
    const int lane = tid & 63;
    const int wid  = tid >> 6;           // 0=i_g, 1=o_g, 2=z (gate owner)
    const int bid  = blockIdx.x;
    const int g    = bid & 7;            // batch group (XCD-affine: bid%8 -> XCD)
    const int idx  = bid >> 3;           // 0..31: 16-col slice within group
    const int col0 = idx << 4;

    __shared__ unsigned short x_tile[16][520];
    __shared__ unsigned short hA[16][520];    // h0_{i-1}
    __shared__ unsigned short hB[16][520];    // h1_{i-2}
    __shared__ float proj[2][3][16][17];

    for (int i = tid; i < 16*520; i += NTHREADS) {
        ((unsigned short*)x_tile)[i] = 0;
        ((unsigned short*)hA)[i] = 0;
        ((unsigned short*)hB)[i] = 0;
    }

    const int lrow = lane & 15;
    const int lk   = (lane >> 4) << 3;
    const int wrow = wid*HID + col0 + lrow;

    // ---- weights for both layers in regs ----
    short8 wf0[16], rf0[16], wf1[16], rf1[16];
#pragma unroll
    for (int kc = 0; kc < 16; ++kc) {
        wf0[kc] = load_frag(W + (size_t)wrow*HID + kc*32 + lk);
        rf0[kc] = load_frag(R + (size_t)wrow*HID + kc*32 + lk);
        wf1[kc] = load_frag(W + ((size_t)GATE + wrow)*HID + kc*32 + lk);
        rf1[kc] = load_frag(R + ((size_t)GATE + wrow)*HID + kc*32 + lk);
    }
    const float bias0 = bi[wrow] + bh[wrow];
    const float bias1 = bi[GATE + wrow] + bh[GATE + wrow];

    const int ecol  = lrow;
    const int erow0 = (lane >> 4) << 2;
    const int myl = (wid == 1) ? 1 : 0;
    const float fgv = sigmoidf_(fw[(size_t)myl*HID + col0 + ecol]);
    float creg[4];
#pragma unroll
    for (int q = 0; q < 4; ++q) {
        int r = erow0 + q;
        creg[q] = (r < GROWS) ? c0[((size_t)myl*BATCH + g*GROWS + r)*HID + col0 + ecol] : 0.0f;
    }

    // ---- stage x_0 (bf16) and h0 inits ----
    {
        const unsigned short* xp = xb + (size_t)g*GROWS*HID;
        for (int w = tid; w < GROWS*HID/8; w += NTHREADS) {
            int r = w >> 6, c8 = (w & 63) << 3;
            *(short8*)(&x_tile[r][c8]) = *(const short8*)(xp + (size_t)r*HID + c8);
        }
        const float* hp0 = h0 + (size_t)g*GROWS*HID;
        const float* hp1 = h0 + ((size_t)BATCH + g*GROWS)*HID;
        for (int w = tid; w < GROWS*HID/4; w += NTHREADS) {
            int r = w >> 7, c4 = (w & 127) << 2;
            floatx4 va_ = *(const floatx4*)(hp0 + (size_t)r*HID + c4);
            floatx4 vb_ = *(const floatx4*)(hp1 + (size_t)r*HID + c4);
            short4v pa, pb;
#pragma unroll
            for (int j = 0; j < 4; ++j) { pa[j] = (short)f2bf(va_[j]); pb[j] = (short)f2bf(vb_[j]); }
            *(short4v*)(&hA[r][c4]) = pa;
            *(short4v*)(&hB[r][c4]) = pb;
        }
    }
    __syncthreads();

    int budget = 1 << 22;

    for (int i = 0; i <= TSTEPS; ++i) {
        // ---- Phase 1: gate GEMMs (4 independent MFMA chains) ----
        floatx4 a0a = {0,0,0,0}, a0b = {0,0,0,0}, a1a = {0,0,0,0}, a1b = {0,0,0,0};
#pragma unroll
        for (int kc = 0; kc < 16; ++kc) {
            short8 afh = *(const short8*)(&hA[lrow][kc*32 + lk]);
            if (i < TSTEPS) {
                short8 afx = *(const short8*)(&x_tile[lrow][kc*32 + lk]);
                a0a = __builtin_amdgcn_mfma_f32_16x16x32_bf16(afx, wf0[kc], a0a, 0, 0, 0);
                a0b = __builtin_amdgcn_mfma_f32_16x16x32_bf16(afh, rf0[kc], a0b, 0, 0, 0);
            }
            if (i >= 1) {
                short8 afb = *(const short8*)(&hB[lrow][kc*32 + lk]);
                a1a = __builtin_amdgcn_mfma_f32_16x16x32_bf16(afh, wf1[kc], a1a, 0, 0, 0);
                a1b = __builtin_amdgcn_mfma_f32_16x16x32_bf16(afb, rf1[kc], a1b, 0, 0, 0);
            }
        }
#pragma unroll
        for (int q = 0; q < 4; ++q) {
            proj[0][wid][erow0 + q][ecol] = sigmoidf_(a0a[q] + a0b[q] + bias0);
            proj[1][wid][erow0 + q][ecol] = sigmoidf_(a1a[q] + a1b[q] + bias1);
        }
        __syncthreads();   // B1

        // ---- Phase 2: state update + packed data publish ----
        if (wid < 2) {
            const int t = i - wid;
            if (t >= 0 && t < TSTEPS) {
                unsigned* ring = (wid == 0) ? ring0 : ring1;
                const int slot = t & 1;
                unsigned* rbase = ring + ((size_t)slot*BATCH + g*GROWS)*(HID/2);
#pragma unroll
                for (int q = 0; q < 4; ++q) {
                    const int r = erow0 + q;
                    const float ig = proj[wid][0][r][ecol];
                    const float og = proj[wid][1][r][ecol];
                    const float zz = proj[wid][2][r][ecol];
                    const float c  = creg[q]*fgv + zz - ig;
                    creg[q] = c;
                    const float h  = sigmoidf_(c) - og;
                    // neighbor-column h via lane^1 swizzle, pack 2xbf16
                    const unsigned hu = __float_as_uint(h);
                    const unsigned pu = (unsigned)__builtin_amdgcn_ds_swizzle((int)hu, 0x041F);
                    const float hp = __uint_as_float(pu);
                    unsigned word;
                    asm volatile("v_cvt_pk_bf16_f32 %0, %1, %2" : "=v"(word) : "v"(h), "v"(hp));
                    if (r < GROWS) {
                        if ((ecol & 1) == 0)
                            __hip_atomic_store(rbase + (size_t)r*(HID/2) + ((col0 + ecol) >> 1),
                                               word, __ATOMIC_RELAXED, __HIP_MEMORY_SCOPE_AGENT);
                        if (wid == 1)
                            out[((size_t)t*BATCH + g*GROWS + r)*HID + col0 + ecol] = h;
                        if (t == TSTEPS - 1) {
                            const size_t fo = (size_t)TSTEPS*BATCH*HID
                                            + ((size_t)wid*BATCH + g*GROWS + r)*HID + col0 + ecol;
                            out[fo] = h;                        // h_f
                            out[fo + (size_t)2*BATCH*HID] = c;  // c_f
                        }
                    }
                }
            }
        }
        asm volatile("s_waitcnt vmcnt(0)" ::: "memory");
        __syncthreads();   // B2: all waves' ring stores are LLC-complete

        if (tid == 0 && i < TSTEPS)
            __hip_atomic_store(sent + ((size_t)g*GCUS + idx)*SENT_STRIDE, (unsigned)(i + 1),
                               __ATOMIC_RELAXED, __HIP_MEMORY_SCOPE_AGENT);

        // ---- Phase 3: waves 0/1 stage x_{i+1}; wave 2 polls sentinels ----
        if (wid < 2 && i + 1 < TSTEPS) {
            const unsigned short* xp = xb + ((size_t)(i+1)*BATCH + g*GROWS)*HID;
#pragma unroll
            for (int k = 0; k < 4; ++k) {
                const int w = tid + k*128;
                if (w < GROWS*HID/8) {
                    const int r = w >> 6, c8 = (w & 63) << 3;
                    *(short8*)(&x_tile[r][c8]) = *(const short8*)(xp + (size_t)r*HID + c8);
                }
            }
        }
        if (wid == 2 && i < TSTEPS) {
            const unsigned want = (unsigned)(i + 1);
            const unsigned* sp = sent + (size_t)g*GCUS*SENT_STRIDE;
            while (true) {
                unsigned v = 0xFFFFFFFFu;
                if (lane < GCUS)
                    v = __hip_atomic_load(sp + (size_t)lane*SENT_STRIDE,
                                          __ATOMIC_RELAXED, __HIP_MEMORY_SCOPE_AGENT);
                const bool ok = (lane >= GCUS) || (v >= want);
                if (__all((int)ok) || --budget <= 0) break;
            }
        }
        __syncthreads();   // B3: sentinel observed => LLC data fresh for ALL waves

        // ---- Phase 4: one batched data sweep + LDS stash ----
        if (i < TSTEPS) {
            const int nw = (i >= 1) ? 2*GROWS*(HID/2) : GROWS*(HID/2);
            const unsigned* pA = ring0 + ((size_t)(i & 1)*BATCH + g*GROWS)*(HID/2);
            const unsigned* pB = ring1 + ((size_t)((i - 1) & 1)*BATCH + g*GROWS)*(HID/2);
            unsigned va[DATAW];
#pragma unroll
            for (int k = 0; k < DATAW; ++k) {
                const int w = tid + k*NTHREADS;
                if (w < nw) {
                    const unsigned* p = ((w < GROWS*(HID/2)) ? pA : pB) + (w & (GROWS*(HID/2) - 1));
                    va[k] = __hip_atomic_load(p, __ATOMIC_RELAXED, __HIP_MEMORY_SCOPE_AGENT);
                }
            }
#pragma unroll
            for (int k = 0; k < DATAW; ++k) {
                const int w = tid + k*NTHREADS;
                if (w < nw) {
                    const int r = (w >> 8) & 7, cp = w & 255;
                    if (w < GROWS*(HID/2)) *(unsigned*)(&hA[r][cp*2]) = va[k];
                    else                   *(unsigned*)(&hB[r][cp*2]) = va[k];
                }
            }
        }
        __syncthreads();   // B4
    }
}

extern "C" void kernel_launch(void* const* d_in, const int* in_sizes, int n_in,
                              void* d_out, int out_size, void* d_ws, size_t ws_size,
                              hipStream_t stream)
{
    (void)in_sizes; (void)n_in; (void)out_size; (void)ws_size;
    const float* x  = (const float*)d_in[0];
    const float* h0 = (const float*)d_in[1];
    const float* c0 = (const float*)d_in[2];
    const float* W  = (const float*)d_in[3];
    const float* R  = (const float*)d_in[4];
    const float* bi = (const float*)d_in[5];
    const float* bh = (const float*)d_in[6];
    const float* fw = (const float*)d_in[7];
    float* out = (float*)d_out;

    unsigned* sent  = (unsigned*)d_ws;                                 // 4 KB used
    unsigned* ring0 = (unsigned*)((char*)d_ws + 8192);                 // 128 KB
    unsigned* ring1 = ring0 + RING_WORDS;                              // 128 KB
    unsigned short* xbuf = (unsigned short*)((char*)d_ws + 512*1024);  // 64 MB

    hipMemsetAsync(d_ws, 0, 8192, stream);   // sentinels := 0 (replay-safe)

    xconvert<<<dim3(TSTEPS*BATCH*HID/(256*8)), dim3(256), 0, stream>>>(x, xbuf);

    sublstm_fused<<<dim3(NGROUPS*GCUS), dim3(NTHREADS), 0, stream>>>(
        xbuf, W, R, bi, bh, fw, h0, c0, sent, ring0, ring1, out);
}